// Round 12
// baseline (133.341 us; speedup 1.0000x reference)
//
#include <hip/hip_runtime.h>
#include <stdint.h>

#define BB 2
#define SS 2048
#define DD 1024
#define HH 16
#define HDIM 64
#define MTOT (BB*SS)
// 0.125 * log2(e): softmax computed in exp2 domain
#define QK_SCALE_LOG2E 0.180336880f

typedef unsigned short u16;
typedef __attribute__((ext_vector_type(8))) __bf16 bf16x8;
typedef __attribute__((ext_vector_type(4))) float f32x4;

static __device__ __forceinline__ float exp2_hw(float x) {
    return __builtin_amdgcn_exp2f(x);   // v_exp_f32: D = 2^S0
}

static __device__ __forceinline__ u16 f2bu(float f) {
    union { float f; uint32_t u; } c; c.f = f;
    uint32_t u = c.u + 0x7fffu + ((c.u >> 16) & 1u);
    return (u16)(u >> 16);
}

static __device__ __forceinline__ u16 f2b_hw(float f) {
    __bf16 b = (__bf16)f;
    union { __bf16 b; u16 u; } c; c.b = b;
    return c.u;
}

static __device__ __forceinline__ uint32_t cvt_pk_bf16(float lo, float hi) {
    uint32_t r;
    asm("v_cvt_pk_bf16_f32 %0, %1, %2" : "=v"(r) : "v"(lo), "v"(hi));
    return r;
}

static __device__ __forceinline__ void gload_lds16(const void* g, void* l) {
    __builtin_amdgcn_global_load_lds(
        (const __attribute__((address_space(1))) uint32_t*)(g),
        (__attribute__((address_space(3))) uint32_t*)(l),
        16, 0, 0);
}

// ---------------- merged prologue: convert + weight transpose --------------
// (Round-9 version, verbatim.)
__global__ void k_prep(const float* __restrict__ x, u16* __restrict__ xb,
                       const float* __restrict__ Wq, const float* __restrict__ Wk,
                       const float* __restrict__ Wv, const float* __restrict__ Wo,
                       u16* __restrict__ Wqkv_t, u16* __restrict__ Wo_t) {
    const int which = blockIdx.z;
    if (which == 4) {
        const int tid = (blockIdx.y * 32 + blockIdx.x) * 256 + threadIdx.y * 32 + threadIdx.x;
        #pragma unroll
        for (int r = 0; r < 4; ++r) {
            const int i = (tid + r * 262144) * 4;
            float4 v = *(const float4*)(x + i);
            ushort4 o;
            o.x = f2bu(v.x); o.y = f2bu(v.y); o.z = f2bu(v.z); o.w = f2bu(v.w);
            *(ushort4*)(xb + i) = o;
        }
        return;
    }
    __shared__ float tile[32][33];
    const float* W = (which == 0) ? Wq : (which == 1) ? Wk : (which == 2) ? Wv : Wo;
    u16* dst = (which < 3) ? (Wqkv_t + (size_t)which * DD * DD) : Wo_t;
    const int n0 = blockIdx.x * 32, k0 = blockIdx.y * 32;
    const int tx = threadIdx.x, ty = threadIdx.y;
    #pragma unroll
    for (int i = 0; i < 32; i += 8)
        tile[ty + i][tx] = W[(size_t)(k0 + ty + i) * DD + (n0 + tx)];
    __syncthreads();
    #pragma unroll
    for (int i = 0; i < 32; i += 8)
        dst[(size_t)(n0 + ty + i) * DD + (k0 + tx)] = f2bu(tile[tx][ty + i]);
}

// ---------------- fused QKV projection GEMM: 128x128, 3-buffer pipeline ----
// Ported onto the round-11 k_gemm_out skeleton (the freshly-validated best
// per-FLOP GEMM structure here: 818 TF vs the 256x192 deep pipeline's 660).
// 128^2 tile, 256 thr / 4 waves (64x64 per wave), A/B triple-buffered,
// tail-vmcnt(8) pattern: stage(t+2) first (loads fly under MFMA), compute
// buf t, vmcnt(8) drains stage t+1 leaving stage t+2's 8 loads in flight
// across the barrier. Grid 24x32 = 768 blocks (3 rounds of 256 CUs).
// Bijective XCD swizzle: per XCD an 8(m) x 12(n) sub-grid -> A 2MB + B 3MB
// working set. Epilogue: 128-wide n-tiles sit entirely inside one of
// q/k/v (128 | 1024) -> wave-uniform segment select per block.
__global__ __launch_bounds__(256, 2) void k_gemm_qkv(
    const u16* __restrict__ Xb, const u16* __restrict__ Wt,
    const float* __restrict__ bq, const float* __restrict__ bk_, const float* __restrict__ bv,
    u16* __restrict__ Qb, u16* __restrict__ Kb, u16* __restrict__ Vt)
{
    __shared__ u16 As3[3][128 * 64];   // 48KB: A triple-buffer
    __shared__ u16 Bs3[3][128 * 64];   // 48KB: B triple-buffer
    const int flat = blockIdx.y * 24 + blockIdx.x;
    const int xcd = flat & 7, idx = flat >> 3;          // idx in [0,96)
    const int by = ((xcd >> 1) << 3) + idx / 12;        // [0,32)
    const int bx = ((xcd & 1) * 12) + idx % 12;         // [0,24)
    const int m0 = by << 7, n0 = bx << 7;
    const int t = threadIdx.x;
    const int lane = t & 63, w = t >> 6;
    const int wm = (w >> 1) << 6, wn = (w & 1) << 6;
    const int lr = lane & 15, lg = lane >> 4;

    f32x4 acc[4][4] = {};

    // 8 loads/thread per stage (4 A + 4 B)
    auto stage = [&](int buf, int kt) {
        #pragma unroll
        for (int i = 0; i < 4; ++i) {
            int off = (t + (i << 8)) << 4;
            int row = off >> 7, colb = off & 127;
            int scol = colb ^ ((row & 7) << 4);
            gload_lds16(Xb + (size_t)(m0 + row) * DD + (kt << 6) + (scol >> 1), (char*)As3[buf] + off);
            gload_lds16(Wt + (size_t)(n0 + row) * DD + (kt << 6) + (scol >> 1), (char*)Bs3[buf] + off);
        }
    };

    // prologue: tiles 0,1; drain tile 0 (8 oldest), keep tile 1 in flight
    stage(0, 0); stage(1, 1);
    asm volatile("s_waitcnt vmcnt(8)" ::: "memory");
    __builtin_amdgcn_sched_barrier(0);
    __builtin_amdgcn_s_barrier();

    int cur = 0;
    #pragma unroll 1
    for (int kt = 0; kt < 16; ++kt) {
        const int nxt = (cur == 2) ? 0 : cur + 1;
        const int nx2 = (nxt == 2) ? 0 : nxt + 1;
        if (kt + 2 < 16) stage(nx2, kt + 2);   // buf of kt-1, WAR 1 barrier back

        __builtin_amdgcn_s_setprio(1);
        #pragma unroll
        for (int ks = 0; ks < 2; ++ks) {
            bf16x8 a[4], b[4];
            #pragma unroll
            for (int i = 0; i < 4; ++i) {
                const int row = wm + (i << 4) + lr;
                a[i] = *(const bf16x8*)((const char*)As3[cur] + row * 128 + (((ks << 6) + (lg << 4)) ^ ((row & 7) << 4)));
            }
            #pragma unroll
            for (int i = 0; i < 4; ++i) {
                const int row = wn + (i << 4) + lr;
                b[i] = *(const bf16x8*)((const char*)Bs3[cur] + row * 128 + (((ks << 6) + (lg << 4)) ^ ((row & 7) << 4)));
            }
            #pragma unroll
            for (int mi = 0; mi < 4; ++mi)
                #pragma unroll
                for (int ni = 0; ni < 4; ++ni)
                    acc[mi][ni] = __builtin_amdgcn_mfma_f32_16x16x32_bf16(a[mi], b[ni], acc[mi][ni], 0, 0, 0);
        }
        __builtin_amdgcn_s_setprio(0);

        // counted wait BEFORE barrier: tile kt+1 landed for all waves;
        // tile kt+2's 8 loads stay in flight across the barrier
        if (kt < 15) {
            if (kt + 2 < 16) { asm volatile("s_waitcnt vmcnt(8)" ::: "memory"); }
            else             { asm volatile("s_waitcnt vmcnt(0)" ::: "memory"); }
            __builtin_amdgcn_sched_barrier(0);
            __builtin_amdgcn_s_barrier();
        }
        cur = nxt;
    }

    // epilogue: whole block lies inside one of q/k/v (seg = bx>>3)
    const int seg = bx >> 3;
    #pragma unroll
    for (int mi = 0; mi < 4; ++mi) {
        #pragma unroll
        for (int ni = 0; ni < 4; ++ni) {
            const int n = n0 + wn + (ni << 4) + lr;
            const int mbase = m0 + wm + (mi << 4) + (lg << 2);
            const int b_ = mbase >> 11;
            const int s_ = mbase & 2047;
            const int nn = n & 1023;
            const int hh = nn >> 6, d = nn & 63;
            if (seg == 0) {                      // Q, scaled (exp2-domain softmax)
                const float bias = bq[nn];
                u16* dstp = Qb + (((size_t)b_ * HH + hh) * SS + s_) * HDIM + d;
                #pragma unroll
                for (int r = 0; r < 4; ++r)
                    dstp[(size_t)r * HDIM] = f2bu((acc[mi][ni][r] + bias) * QK_SCALE_LOG2E);
            } else if (seg == 1) {               // K
                const float bias = bk_[nn];
                u16* dstp = Kb + (((size_t)b_ * HH + hh) * SS + s_) * HDIM + d;
                #pragma unroll
                for (int r = 0; r < 4; ++r)
                    dstp[(size_t)r * HDIM] = f2bu(acc[mi][ni][r] + bias);
            } else {                             // V -> transposed [b][h][d][s]
                const float bias = bv[nn];
                ushort4 pk;
                pk.x = f2bu(acc[mi][ni][0] + bias);
                pk.y = f2bu(acc[mi][ni][1] + bias);
                pk.z = f2bu(acc[mi][ni][2] + bias);
                pk.w = f2bu(acc[mi][ni][3] + bias);
                *(ushort4*)(Vt + (((size_t)b_ * HH + hh) * HDIM + d) * SS + s_) = pk;
            }
        }
    }
}

// ---------------- flash attention v4 (round-6 version, verbatim) -----------
// Best measured (42.9us). 8 waves x 16 q-rows, 3-buffer depth-2 prefetch,
// counted vmcnt(2), XCD-grouped; P redistribution fully in-register
// (cvt_pk + permlane32/16 swaps); no P LDS round-trip.
__global__ __launch_bounds__(512, 4) void k_attn(
    const u16* __restrict__ Qb, const u16* __restrict__ Kb, const u16* __restrict__ Vt,
    const int* __restrict__ qmask, const int* __restrict__ kmask,
    u16* __restrict__ X2)
{
    // XCD-aware decode: hw round-robins blockIdx over 8 XCDs
    const int i = blockIdx.x;
    const int xcd = i & 7, j = i >> 3;          // j in [0,64)
    const int qt = j & 15;
    const int bh = xcd + ((j >> 4) << 3);       // {xcd, xcd+8, xcd+16, xcd+24}
    const int b_ = bh >> 4;
    const int h = bh & 15;

    const int t = threadIdx.x;
    const int lane = t & 63, w = t >> 6;
    const int lr = lane & 15, lg = lane >> 4;

    __shared__ u16 Ks[3][64 * 64];   // 24KB
    __shared__ u16 Vs[3][64 * 64];   // 24KB  (V^T tile: [d][k])

    const int q0 = qt << 7;
    const size_t bhs = (size_t)b_ * HH + h;
    const u16* Qbase = Qb + bhs * SS * HDIM;
    const char* KbaseB = (const char*)(Kb + bhs * SS * HDIM);
    const char* VbaseB = (const char*)(Vt + bhs * HDIM * SS);

    // fully-masked query tile (prefix mask): write zeros, done
    if (qmask[b_ * SS + q0] == 0) {
        #pragma unroll
        for (int r = 0; r < 4; ++r) {
            const int q = q0 + (w << 4) + (lg << 2) + r;
            #pragma unroll
            for (int nf = 0; nf < 4; ++nf)
                X2[((size_t)b_ * SS + q) * DD + (h << 6) + (nf << 4) + lr] = 0;
        }
        return;
    }

    // number of valid 64-key tiles (prefix mask); uniform across waves
    int kv = (lane < 32) ? kmask[b_ * SS + (lane << 6)] : 0;
    unsigned long long bal = __ballot(kv != 0);
    const int nkt = __popcll(bal);

    bf16x8 qf[2];
    #pragma unroll
    for (int ks = 0; ks < 2; ++ks)
        qf[ks] = *(const bf16x8*)(Qbase + (size_t)(q0 + (w << 4) + lr) * HDIM + (ks << 5) + (lg << 3));

    // all-ones B fragment for row-sum l via MFMA
    bf16x8 vones;
    #pragma unroll
    for (int i2 = 0; i2 < 8; ++i2) vones[i2] = (__bf16)1.0f;

    f32x4 o[4] = {};
    f32x4 lacc = {};

    // stage tile at key-offset kb into buffer buf: 512 threads x 16B covers
    // one 8KB tile each for K and V (1 gload_lds each per thread)
    auto stage = [&](int buf, int kb) {
        const int off = t << 4;               // bytes 0..8191
        const int row = off >> 7, colb = off & 127;
        const int scol = colb ^ ((row & 7) << 4);   // pre-swizzled source
        gload_lds16(KbaseB + (size_t)(kb + row) * 128 + scol, (char*)Ks[buf] + off);
        gload_lds16(VbaseB + ((size_t)row * SS + (size_t)kb) * 2 + scol, (char*)Vs[buf] + off);
    };

    // prologue: depth-2 prefetch (tiles 0 and 1)
    if (nkt > 0) stage(0, 0);
    if (nkt > 1) stage(1, 64);
    if (nkt > 1) { asm volatile("s_waitcnt vmcnt(2)" ::: "memory"); }  // tile0 landed
    else         { asm volatile("s_waitcnt vmcnt(0)" ::: "memory"); }
    __builtin_amdgcn_sched_barrier(0);
    __builtin_amdgcn_s_barrier();

    int cur = 0;
    #pragma unroll 1
    for (int kt = 0; kt < nkt; ++kt) {
        const int kb = kt << 6;
        const int nxt = (cur == 2) ? 0 : cur + 1;
        const int nx2 = (nxt == 2) ? 0 : nxt + 1;
        if (kt + 2 < nkt) stage(nx2, kb + 128);   // tile kt+2 -> buf of kt-1 (WAR ok)

        // S^T = K Q^T: sf[f] rows = k (f*16 + lg*4 + r), cols = q (lr)
        f32x4 sf[4] = {};
        __builtin_amdgcn_s_setprio(1);
        #pragma unroll
        for (int ks = 0; ks < 2; ++ks) {
            #pragma unroll
            for (int f = 0; f < 4; ++f) {
                const int krow = (f << 4) + lr;
                const int kcol = ((ks << 6) + (lg << 4)) ^ ((krow & 7) << 4);
                bf16x8 kf = *(const bf16x8*)((const char*)Ks[cur] + krow * 128 + kcol);
                sf[f] = __builtin_amdgcn_mfma_f32_16x16x32_bf16(kf, qf[ks], sf[f], 0, 0, 0);
            }
        }
        __builtin_amdgcn_s_setprio(0);
        // key mask: only the last tile can be partial (prefix mask)
        if (kt == nkt - 1) {
            #pragma unroll
            for (int f = 0; f < 4; ++f) {
                #pragma unroll
                for (int r = 0; r < 4; ++r) {
                    if (kmask[b_ * SS + kb + (f << 4) + (lg << 2) + r] == 0)
                        sf[f][r] = -1e30f;
                }
            }
        }
        // P = exp2(S) (no max subtraction: scores bounded, f32 has headroom)
        #pragma unroll
        for (int f = 0; f < 4; ++f)
            #pragma unroll
            for (int r = 0; r < 4; ++r)
                sf[f][r] = exp2_hw(sf[f][r]);

        // in-register P -> PV A-fragments (no LDS round-trip)
        uint32_t wv[4][2];
        #pragma unroll
        for (int f = 0; f < 4; ++f) {
            wv[f][0] = cvt_pk_bf16(sf[f][0], sf[f][1]);
            wv[f][1] = cvt_pk_bf16(sf[f][2], sf[f][3]);
        }
        bf16x8 pa[2];
        #pragma unroll
        for (int ks2 = 0; ks2 < 2; ++ks2) {
            uint32_t u0, u1, u2, u3;
            {
                uint32_t A = wv[2 * ks2][0], B = wv[2 * ks2 + 1][0];
                asm("v_permlane32_swap_b32 %0, %1" : "+v"(A), "+v"(B));
                asm("v_permlane16_swap_b32 %0, %1" : "+v"(A), "+v"(B));
                u0 = A; u2 = B;
            }
            {
                uint32_t A = wv[2 * ks2][1], B = wv[2 * ks2 + 1][1];
                asm("v_permlane32_swap_b32 %0, %1" : "+v"(A), "+v"(B));
                asm("v_permlane16_swap_b32 %0, %1" : "+v"(A), "+v"(B));
                u1 = A; u3 = B;
            }
            union { uint32_t q[4]; bf16x8 v; } cv;
            cv.q[0] = u0; cv.q[1] = u1; cv.q[2] = u2; cv.q[3] = u3;
            pa[ks2] = cv.v;
        }

        // O += P V ; l += P . ones   (A = pa[ks] in registers, B = V^T / ones)
        __builtin_amdgcn_s_setprio(1);
        #pragma unroll
        for (int ks = 0; ks < 2; ++ks) {
            lacc = __builtin_amdgcn_mfma_f32_16x16x32_bf16(pa[ks], vones, lacc, 0, 0, 0);
            #pragma unroll
            for (int nf = 0; nf < 4; ++nf) {
                const int vrow = (nf << 4) + lr;
                const int vcol = ((ks << 6) + (lg << 4)) ^ ((vrow & 7) << 4);
                bf16x8 vb = *(const bf16x8*)((const char*)Vs[cur] + vrow * 128 + vcol);
                o[nf] = __builtin_amdgcn_mfma_f32_16x16x32_bf16(pa[ks], vb, o[nf], 0, 0, 0);
            }
        }
        __builtin_amdgcn_s_setprio(0);

        // counted wait BEFORE barrier: tile kt+1 must be landed (all waves),
        // tile kt+2's 2 loads may stay in flight
        if (kt + 2 < nkt) { asm volatile("s_waitcnt vmcnt(2)" ::: "memory"); }
        else              { asm volatile("s_waitcnt vmcnt(0)" ::: "memory"); }
        __builtin_amdgcn_sched_barrier(0);
        __builtin_amdgcn_s_barrier();
        cur = nxt;
    }

    // normalize, apply query mask, store bf16 into X2 [b][s][h*64+d]
    #pragma unroll
    for (int r = 0; r < 4; ++r) {
        const int q = q0 + (w << 4) + (lg << 2) + r;
        float l = lacc[r];
        float inv = (l > 0.f) ? __builtin_amdgcn_rcpf(l) : 0.f;
        if (qmask[b_ * SS + q] == 0) inv = 0.f;
        #pragma unroll
        for (int nf = 0; nf < 4; ++nf)
            X2[((size_t)b_ * SS + q) * DD + (h << 6) + (nf << 4) + lr] = f2b_hw(o[nf][r] * inv);
    }
}

// ---------------- output projection GEMM + bias -> fp32 --------------------
// (Round-11 version, verbatim — XCD-swizzled 128^2, 3-buffer tail-vmcnt.)
__global__ __launch_bounds__(256, 2) void k_gemm_out(
    const u16* __restrict__ X2, const u16* __restrict__ Wot,
    const float* __restrict__ bo, float* __restrict__ out)
{
    __shared__ u16 As3[3][128 * 64];   // 48KB: A triple-buffer
    __shared__ u16 Bs3[3][128 * 64];   // 48KB: B triple-buffer
    const int flat = blockIdx.y * 8 + blockIdx.x;
    const int xcd = flat & 7, idx = flat >> 3;
    const int by = (xcd << 2) + (idx >> 3);     // [0,32)
    const int bx = idx & 7;                     // [0,8)
    const int m0 = by * 128, n0 = bx * 128;
    const int t = threadIdx.x;
    const int lane = t & 63, w = t >> 6;
    const int wm = (w >> 1) << 6, wn = (w & 1) << 6;
    const int lr = lane & 15, lg = lane >> 4;

    f32x4 acc[4][4] = {};

    // 8 loads/thread per stage (4 A + 4 B)
    auto stage = [&](int buf, int kt) {
        #pragma unroll
        for (int i = 0; i < 4; ++i) {
            int off = (t + (i << 8)) << 4;
            int row = off >> 7, colb = off & 127;
            int scol = colb ^ ((row & 7) << 4);
            gload_lds16(X2 + (size_t)(m0 + row) * DD + (kt << 6) + (scol >> 1), (char*)As3[buf] + off);
            gload_lds16(Wot + (size_t)(n0 + row) * DD + (kt << 6) + (scol >> 1), (char*)Bs3[buf] + off);
        }
    };

    // prologue: tiles 0,1; drain tile 0 (8 oldest), keep tile 1 in flight
    stage(0, 0); stage(1, 1);
    asm volatile("s_waitcnt vmcnt(8)" ::: "memory");
    __builtin_amdgcn_sched_barrier(0);
    __builtin_amdgcn_s_barrier();

    int cur = 0;
    #pragma unroll 1
    for (int kt = 0; kt < 16; ++kt) {
        const int nxt = (cur == 2) ? 0 : cur + 1;
        const int nx2 = (nxt == 2) ? 0 : nxt + 1;
        if (kt + 2 < 16) stage(nx2, kt + 2);   // buf of kt-1, WAR 1 barrier back

        __builtin_amdgcn_s_setprio(1);
        #pragma unroll
        for (int ks = 0; ks < 2; ++ks) {
            bf16x8 a[4], b[4];
            #pragma unroll
            for (int i = 0; i < 4; ++i) {
                const int row = wm + (i << 4) + lr;
                a[i] = *(const bf16x8*)((const char*)As3[cur] + row * 128 + (((ks << 6) + (lg << 4)) ^ ((row & 7) << 4)));
            }
            #pragma unroll
            for (int i = 0; i < 4; ++i) {
                const int row = wn + (i << 4) + lr;
                b[i] = *(const bf16x8*)((const char*)Bs3[cur] + row * 128 + (((ks << 6) + (lg << 4)) ^ ((row & 7) << 4)));
            }
            #pragma unroll
            for (int mi = 0; mi < 4; ++mi)
                #pragma unroll
                for (int ni = 0; ni < 4; ++ni)
                    acc[mi][ni] = __builtin_amdgcn_mfma_f32_16x16x32_bf16(a[mi], b[ni], acc[mi][ni], 0, 0, 0);
        }
        __builtin_amdgcn_s_setprio(0);

        // counted wait BEFORE barrier: tile kt+1 landed for all waves;
        // tile kt+2's 8 loads stay in flight across the barrier
        if (kt < 15) {
            if (kt + 2 < 16) { asm volatile("s_waitcnt vmcnt(8)" ::: "memory"); }
            else             { asm volatile("s_waitcnt vmcnt(0)" ::: "memory"); }
            __builtin_amdgcn_sched_barrier(0);
            __builtin_amdgcn_s_barrier();
        }
        cur = nxt;
    }

    #pragma unroll
    for (int mi = 0; mi < 4; ++mi) {
        #pragma unroll
        for (int ni = 0; ni < 4; ++ni) {
            const int n = n0 + wn + (ni << 4) + lr;
            const int mbase = m0 + wm + (mi << 4) + (lg << 2);
            const float bias = bo[n];
            #pragma unroll
            for (int r = 0; r < 4; ++r)
                out[(size_t)(mbase + r) * DD + n] = acc[mi][ni][r] + bias;
        }
    }
}

extern "C" void kernel_launch(void* const* d_in, const int* in_sizes, int n_in,
                              void* d_out, int out_size, void* d_ws, size_t ws_size,
                              hipStream_t stream) {
    const float* hs = (const float*)d_in[0];
    const float* Wq = (const float*)d_in[1];
    const float* bq = (const float*)d_in[2];
    const float* Wk = (const float*)d_in[3];
    const float* bk = (const float*)d_in[4];
    const float* Wv = (const float*)d_in[5];
    const float* bv = (const float*)d_in[6];
    const float* Wo = (const float*)d_in[7];
    const float* bo = (const float*)d_in[8];
    const int* qm = (const int*)d_in[9];
    const int* km = (const int*)d_in[10];
    float* out = (float*)d_out;

    char* ws = (char*)d_ws;
    const size_t MB = 1024 * 1024;
    u16* Xb  = (u16*)(ws + 0);        // [4096][1024]        8 MB
    u16* Wt3 = (u16*)(ws + 8 * MB);   // [3072][1024] q|k|v  6 MB
    u16* Wot = (u16*)(ws + 14 * MB);  // [1024][1024]        2 MB
    u16* Qb  = (u16*)(ws + 16 * MB);  // [B][H][S][HD]       8 MB
    u16* Kb  = (u16*)(ws + 24 * MB);  // [B][H][S][HD]       8 MB
    u16* Vt  = (u16*)(ws + 32 * MB);  // [B][H][HD][S]       8 MB
    u16* X2  = (u16*)(ws + 40 * MB);  // [4096][1024]        8 MB

    k_prep<<<dim3(32, 32, 5), dim3(32, 8), 0, stream>>>(hs, Xb, Wq, Wk, Wv, Wo, Wt3, Wot);
    k_gemm_qkv<<<dim3(24, 32), dim3(256), 0, stream>>>(Xb, Wt3, bq, bk, bv, Qb, Kb, Vt);
    k_attn<<<dim3(512), dim3(512), 0, stream>>>(Qb, Kb, Vt, qm, km, X2);
    k_gemm_out<<<dim3(8, 32), dim3(256), 0, stream>>>(X2, Wot, bo, out);
}

// Round 13
// 104.512 us; speedup vs baseline: 1.2758x; 1.2758x over previous
//
#include <hip/hip_runtime.h>
#include <stdint.h>

#define BB 2
#define SS 2048
#define DD 1024
#define HH 16
#define HDIM 64
#define MTOT (BB*SS)
// 0.125 * log2(e): softmax computed in exp2 domain
#define QK_SCALE_LOG2E 0.180336880f

typedef unsigned short u16;
typedef __attribute__((ext_vector_type(8))) __bf16 bf16x8;
typedef __attribute__((ext_vector_type(4))) float f32x4;

static __device__ __forceinline__ float exp2_hw(float x) {
    return __builtin_amdgcn_exp2f(x);   // v_exp_f32: D = 2^S0
}

static __device__ __forceinline__ u16 f2bu(float f) {
    union { float f; uint32_t u; } c; c.f = f;
    uint32_t u = c.u + 0x7fffu + ((c.u >> 16) & 1u);
    return (u16)(u >> 16);
}

static __device__ __forceinline__ u16 f2b_hw(float f) {
    __bf16 b = (__bf16)f;
    union { __bf16 b; u16 u; } c; c.b = b;
    return c.u;
}

static __device__ __forceinline__ uint32_t cvt_pk_bf16(float lo, float hi) {
    uint32_t r;
    asm("v_cvt_pk_bf16_f32 %0, %1, %2" : "=v"(r) : "v"(lo), "v"(hi));
    return r;
}

static __device__ __forceinline__ void gload_lds16(const void* g, void* l) {
    __builtin_amdgcn_global_load_lds(
        (const __attribute__((address_space(1))) uint32_t*)(g),
        (__attribute__((address_space(3))) uint32_t*)(l),
        16, 0, 0);
}

// ---------------- merged prologue: convert + weight transpose --------------
// (Round-9 version, verbatim.)
__global__ void k_prep(const float* __restrict__ x, u16* __restrict__ xb,
                       const float* __restrict__ Wq, const float* __restrict__ Wk,
                       const float* __restrict__ Wv, const float* __restrict__ Wo,
                       u16* __restrict__ Wqkv_t, u16* __restrict__ Wo_t) {
    const int which = blockIdx.z;
    if (which == 4) {
        const int tid = (blockIdx.y * 32 + blockIdx.x) * 256 + threadIdx.y * 32 + threadIdx.x;
        #pragma unroll
        for (int r = 0; r < 4; ++r) {
            const int i = (tid + r * 262144) * 4;
            float4 v = *(const float4*)(x + i);
            ushort4 o;
            o.x = f2bu(v.x); o.y = f2bu(v.y); o.z = f2bu(v.z); o.w = f2bu(v.w);
            *(ushort4*)(xb + i) = o;
        }
        return;
    }
    __shared__ float tile[32][33];
    const float* W = (which == 0) ? Wq : (which == 1) ? Wk : (which == 2) ? Wv : Wo;
    u16* dst = (which < 3) ? (Wqkv_t + (size_t)which * DD * DD) : Wo_t;
    const int n0 = blockIdx.x * 32, k0 = blockIdx.y * 32;
    const int tx = threadIdx.x, ty = threadIdx.y;
    #pragma unroll
    for (int i = 0; i < 32; i += 8)
        tile[ty + i][tx] = W[(size_t)(k0 + ty + i) * DD + (n0 + tx)];
    __syncthreads();
    #pragma unroll
    for (int i = 0; i < 32; i += 8)
        dst[(size_t)(n0 + ty + i) * DD + (k0 + tx)] = f2bu(tile[tx][ty + i]);
}

// ---------------- fused QKV projection GEMM: 256x192, reg-pipelined --------
// (Round-10 version, verbatim — best measured. 256 blocks = 1 dispatch
// round, 1 block/CU; A triple-buffer, B double-buffer, vmcnt(7) leash,
// register-fragment pipeline, rolled I$-resident loop. Round-12 showed
// smaller tiles regress: >256 blocks means multiple dispatch rounds that
// re-fetch A/B panels through L2 (FETCH 29->47MB) with no co-residency.)
#define VMH(N) do { asm volatile("s_waitcnt vmcnt(" #N ")" ::: "memory"); \
                    __builtin_amdgcn_sched_barrier(0); } while (0)

#define PHX(AFRC, BFRC, MFQ, RDNEXT, STAGECODE)                               \
  { RDNEXT;                                                                   \
    STAGECODE;                                                                \
    __builtin_amdgcn_s_barrier();                                             \
    __builtin_amdgcn_sched_barrier(0);                                        \
    __builtin_amdgcn_s_setprio(1);                                            \
    _Pragma("unroll") for (int m2 = 0; m2 < 2; ++m2)                          \
      _Pragma("unroll") for (int nf = 0; nf < 3; ++nf)                        \
        _Pragma("unroll") for (int ks = 0; ks < 2; ++ks)                      \
          acc[2*(MFQ)+m2][nf] = __builtin_amdgcn_mfma_f32_16x16x32_bf16(      \
              AFRC[m2][ks], BFRC[nf][ks], acc[2*(MFQ)+m2][nf], 0, 0, 0);      \
    __builtin_amdgcn_s_setprio(0);                                            \
    __builtin_amdgcn_s_barrier();                                             \
  }

__global__ __launch_bounds__(512, 2) void k_gemm_qkv(
    const u16* __restrict__ Xb, const u16* __restrict__ Wt,
    const float* __restrict__ bq, const float* __restrict__ bk_, const float* __restrict__ bv,
    u16* __restrict__ Qb, u16* __restrict__ Kb, u16* __restrict__ Vt)
{
    __shared__ u16 AsA[3][256 * 64];   // 96 KB: A triple-buffer (32 KB each)
    __shared__ u16 BsB[2][192 * 64];   // 48 KB: B double-buffer (24 KB each)

    const int flat = blockIdx.y * 16 + blockIdx.x;
    const int xcd = flat & 7, idx = flat >> 3;
    const int by = ((xcd >> 1) << 2) + (idx >> 3);
    const int bx = ((xcd & 1) << 3) + (idx & 7);
    const int m0 = by << 8, n0 = bx * 192;

    const int t = threadIdx.x;
    const int lane = t & 63, w = t >> 6;
    const int wm = (w >> 2) << 7, wn = (w & 3) * 48;
    const int lr = lane & 15, lg = lane >> 4;

    const u16* Asrc = Xb + (size_t)m0 * DD;
    const u16* Bsrc = Wt + (size_t)n0 * DD;

    f32x4 acc[8][3] = {};
    bf16x8 afr0[2][2], afr1[2][2];     // A-fragment double buffer (cur/next)
    bf16x8 bfr0[3][2], bfr1[3][2];     // B-fragment double buffer (per tile)

    auto stgA = [&](u16* bufp, int half, int tt) {
        #pragma unroll
        for (int r = 0; r < 2; ++r) {
            int off = (t + (r << 9)) << 4;        // bytes 0..16383
            int row = off >> 7, colb = off & 127; // 128B rows
            int scol = colb ^ ((row & 7) << 4);   // pre-swizzled source
            gload_lds16(Asrc + (size_t)((half << 7) + row) * DD + (tt << 6) + (scol >> 1),
                        (char*)bufp + (half << 14) + off);
        }
    };
    auto stgB = [&](u16* bufp, int tt) {
        #pragma unroll
        for (int r = 0; r < 3; ++r) {
            int off = (t + (r << 9)) << 4;        // bytes 0..24575
            int row = off >> 7, colb = off & 127;
            int scol = colb ^ ((row & 7) << 4);
            gload_lds16(Bsrc + (size_t)row * DD + (tt << 6) + (scol >> 1),
                        (char*)bufp + off);
        }
    };

    auto rdA = [&](const u16* bufp, int mf, int ks) {
        const int row = wm + (mf << 4) + lr;
        const int col = ((ks << 6) + (lg << 4)) ^ ((row & 7) << 4);
        return *(const bf16x8*)((const char*)bufp + row * 128 + col);
    };
    auto rdB = [&](const u16* bufp, int nf, int ks) {
        const int row = wn + (nf << 4) + lr;
        const int col = ((ks << 6) + (lg << 4)) ^ ((row & 7) << 4);
        return *(const bf16x8*)((const char*)bufp + row * 128 + col);
    };
    auto rdAq = [&](bf16x8 (&dst)[2][2], const u16* bufp, int q) {
        #pragma unroll
        for (int m2 = 0; m2 < 2; ++m2)
            #pragma unroll
            for (int ks = 0; ks < 2; ++ks)
                dst[m2][ks] = rdA(bufp, 2 * q + m2, ks);
    };
    auto rdBt = [&](bf16x8 (&dst)[3][2], const u16* bufp) {
        #pragma unroll
        for (int nf = 0; nf < 3; ++nf)
            #pragma unroll
            for (int ks = 0; ks < 2; ++ks)
                dst[nf][ks] = rdB(bufp, nf, ks);
    };

    u16* pE = AsA[0]; u16* pO = AsA[1]; u16* pS = AsA[2];
    u16* Bs0 = BsB[0]; u16* Bs1 = BsB[1];

    // prologue: tiles 0 and 1 (A+B each); keep tile1's 7 loads in flight
    stgA(pE, 0, 0); stgA(pE, 1, 0); stgB(Bs0, 0);
    stgA(pO, 0, 1); stgA(pO, 1, 1); stgB(Bs1, 1);
    asm volatile("s_waitcnt vmcnt(7)" ::: "memory");   // tile0 landed
    __builtin_amdgcn_sched_barrier(0);
    __builtin_amdgcn_s_barrier();
    // preload phase-1 fragments (tile 0, quadrant 0 + B tile 0)
    rdAq(afr0, pE, 0);
    rdBt(bfr0, Bs0);

    // rolled main loop: iter j computes tiles 2j (pE, Bs0: ph1-4) and 2j+1
    // (pO, Bs1: ph5-8); stages A(2j+2)->pS (ph1,2), B(2j+2)->Bs0 (ph3),
    // A(2j+3)->pE (ph5,6), B(2j+3)->Bs1 (ph7). Each phase reads NEXT
    // phase's fragments; ph4/ph8 additionally load the next tile's B set.
    #pragma unroll 1
    for (int j = 0; j < 7; ++j) {
        const int tb = 2 * j;
        PHX(afr0, bfr0, 0, { rdAq(afr1, pE, 1); }, { stgA(pS, 0, tb + 2); });
        PHX(afr1, bfr0, 1, { rdAq(afr0, pE, 2); }, { stgA(pS, 1, tb + 2); });
        PHX(afr0, bfr0, 2, { rdAq(afr1, pE, 3); }, { stgB(Bs0, tb + 2); });
        VMH(7);   // drains tile 2j+1's A+B (oldest 7 of 14) before reading pO/Bs1
        PHX(afr1, bfr0, 3, { rdAq(afr0, pO, 0); rdBt(bfr1, Bs1); }, {});
        PHX(afr0, bfr1, 0, { rdAq(afr1, pO, 1); }, { stgA(pE, 0, tb + 3); });
        PHX(afr1, bfr1, 1, { rdAq(afr0, pO, 2); }, { stgA(pE, 1, tb + 3); });
        PHX(afr0, bfr1, 2, { rdAq(afr1, pO, 3); }, { stgB(Bs1, tb + 3); });
        VMH(7);   // drains tile 2j+2's A+B before reading pS/Bs0
        PHX(afr1, bfr1, 3, { rdAq(afr0, pS, 0); rdBt(bfr0, Bs0); }, {});
        // rotate roles: (E,O,S) <- (S,E,O)   [tile t lives in A[t%3]]
        u16* oE = pE; u16* oO = pO; u16* oS = pS;
        pE = oS; pO = oE; pS = oO;
    }
    // peeled final iteration: tiles 14 (pE), 15 (pO); no stages
    PHX(afr0, bfr0, 0, { rdAq(afr1, pE, 1); }, {});
    PHX(afr1, bfr0, 1, { rdAq(afr0, pE, 2); }, {});
    PHX(afr0, bfr0, 2, { rdAq(afr1, pE, 3); }, {});
    VMH(0);   // only tile 15's 7 loads remain in flight; drain before pO/Bs1
    PHX(afr1, bfr0, 3, { rdAq(afr0, pO, 0); rdBt(bfr1, Bs1); }, {});
    PHX(afr0, bfr1, 0, { rdAq(afr1, pO, 1); }, {});
    PHX(afr1, bfr1, 1, { rdAq(afr0, pO, 2); }, {});
    PHX(afr0, bfr1, 2, { rdAq(afr1, pO, 3); }, {});
    PHX(afr1, bfr1, 3, {}, {});

    // epilogue: 192-wide tiles cross q/k/v boundaries; each 16-col fragment
    // is boundary-aligned -> per-fragment wave-uniform segment branch
    #pragma unroll
    for (int mf = 0; mf < 8; ++mf) {
        #pragma unroll
        for (int nf = 0; nf < 3; ++nf) {
            const int n = n0 + wn + (nf << 4) + lr;
            const int mbase = m0 + wm + (mf << 4) + (lg << 2);
            const int b_ = mbase >> 11;
            const int s_ = mbase & 2047;
            const int seg = n >> 10;
            const int nn = n & 1023;
            const int hh = nn >> 6, d = nn & 63;
            if (seg == 0) {                      // Q, scaled (exp2-domain softmax)
                const float bias = bq[nn];
                u16* dstp = Qb + (((size_t)b_ * HH + hh) * SS + s_) * HDIM + d;
                #pragma unroll
                for (int r = 0; r < 4; ++r)
                    dstp[(size_t)r * HDIM] = f2bu((acc[mf][nf][r] + bias) * QK_SCALE_LOG2E);
            } else if (seg == 1) {               // K
                const float bias = bk_[nn];
                u16* dstp = Kb + (((size_t)b_ * HH + hh) * SS + s_) * HDIM + d;
                #pragma unroll
                for (int r = 0; r < 4; ++r)
                    dstp[(size_t)r * HDIM] = f2bu(acc[mf][nf][r] + bias);
            } else {                             // V -> transposed [b][h][d][s]
                const float bias = bv[nn];
                ushort4 pk;
                pk.x = f2bu(acc[mf][nf][0] + bias);
                pk.y = f2bu(acc[mf][nf][1] + bias);
                pk.z = f2bu(acc[mf][nf][2] + bias);
                pk.w = f2bu(acc[mf][nf][3] + bias);
                *(ushort4*)(Vt + (((size_t)b_ * HH + hh) * HDIM + d) * SS + s_) = pk;
            }
        }
    }
}

// ---------------- flash attention v4 (round-6 version, verbatim) -----------
// Best measured (42.9us). 8 waves x 16 q-rows, 3-buffer depth-2 prefetch,
// counted vmcnt(2), XCD-grouped; P redistribution fully in-register
// (cvt_pk + permlane32/16 swaps); no P LDS round-trip.
__global__ __launch_bounds__(512, 4) void k_attn(
    const u16* __restrict__ Qb, const u16* __restrict__ Kb, const u16* __restrict__ Vt,
    const int* __restrict__ qmask, const int* __restrict__ kmask,
    u16* __restrict__ X2)
{
    // XCD-aware decode: hw round-robins blockIdx over 8 XCDs
    const int i = blockIdx.x;
    const int xcd = i & 7, j = i >> 3;          // j in [0,64)
    const int qt = j & 15;
    const int bh = xcd + ((j >> 4) << 3);       // {xcd, xcd+8, xcd+16, xcd+24}
    const int b_ = bh >> 4;
    const int h = bh & 15;

    const int t = threadIdx.x;
    const int lane = t & 63, w = t >> 6;
    const int lr = lane & 15, lg = lane >> 4;

    __shared__ u16 Ks[3][64 * 64];   // 24KB
    __shared__ u16 Vs[3][64 * 64];   // 24KB  (V^T tile: [d][k])

    const int q0 = qt << 7;
    const size_t bhs = (size_t)b_ * HH + h;
    const u16* Qbase = Qb + bhs * SS * HDIM;
    const char* KbaseB = (const char*)(Kb + bhs * SS * HDIM);
    const char* VbaseB = (const char*)(Vt + bhs * HDIM * SS);

    // fully-masked query tile (prefix mask): write zeros, done
    if (qmask[b_ * SS + q0] == 0) {
        #pragma unroll
        for (int r = 0; r < 4; ++r) {
            const int q = q0 + (w << 4) + (lg << 2) + r;
            #pragma unroll
            for (int nf = 0; nf < 4; ++nf)
                X2[((size_t)b_ * SS + q) * DD + (h << 6) + (nf << 4) + lr] = 0;
        }
        return;
    }

    // number of valid 64-key tiles (prefix mask); uniform across waves
    int kv = (lane < 32) ? kmask[b_ * SS + (lane << 6)] : 0;
    unsigned long long bal = __ballot(kv != 0);
    const int nkt = __popcll(bal);

    bf16x8 qf[2];
    #pragma unroll
    for (int ks = 0; ks < 2; ++ks)
        qf[ks] = *(const bf16x8*)(Qbase + (size_t)(q0 + (w << 4) + lr) * HDIM + (ks << 5) + (lg << 3));

    // all-ones B fragment for row-sum l via MFMA
    bf16x8 vones;
    #pragma unroll
    for (int i2 = 0; i2 < 8; ++i2) vones[i2] = (__bf16)1.0f;

    f32x4 o[4] = {};
    f32x4 lacc = {};

    // stage tile at key-offset kb into buffer buf: 512 threads x 16B covers
    // one 8KB tile each for K and V (1 gload_lds each per thread)
    auto stage = [&](int buf, int kb) {
        const int off = t << 4;               // bytes 0..8191
        const int row = off >> 7, colb = off & 127;
        const int scol = colb ^ ((row & 7) << 4);   // pre-swizzled source
        gload_lds16(KbaseB + (size_t)(kb + row) * 128 + scol, (char*)Ks[buf] + off);
        gload_lds16(VbaseB + ((size_t)row * SS + (size_t)kb) * 2 + scol, (char*)Vs[buf] + off);
    };

    // prologue: depth-2 prefetch (tiles 0 and 1)
    if (nkt > 0) stage(0, 0);
    if (nkt > 1) stage(1, 64);
    if (nkt > 1) { asm volatile("s_waitcnt vmcnt(2)" ::: "memory"); }  // tile0 landed
    else         { asm volatile("s_waitcnt vmcnt(0)" ::: "memory"); }
    __builtin_amdgcn_sched_barrier(0);
    __builtin_amdgcn_s_barrier();

    int cur = 0;
    #pragma unroll 1
    for (int kt = 0; kt < nkt; ++kt) {
        const int kb = kt << 6;
        const int nxt = (cur == 2) ? 0 : cur + 1;
        const int nx2 = (nxt == 2) ? 0 : nxt + 1;
        if (kt + 2 < nkt) stage(nx2, kb + 128);   // tile kt+2 -> buf of kt-1 (WAR ok)

        // S^T = K Q^T: sf[f] rows = k (f*16 + lg*4 + r), cols = q (lr)
        f32x4 sf[4] = {};
        __builtin_amdgcn_s_setprio(1);
        #pragma unroll
        for (int ks = 0; ks < 2; ++ks) {
            #pragma unroll
            for (int f = 0; f < 4; ++f) {
                const int krow = (f << 4) + lr;
                const int kcol = ((ks << 6) + (lg << 4)) ^ ((krow & 7) << 4);
                bf16x8 kf = *(const bf16x8*)((const char*)Ks[cur] + krow * 128 + kcol);
                sf[f] = __builtin_amdgcn_mfma_f32_16x16x32_bf16(kf, qf[ks], sf[f], 0, 0, 0);
            }
        }
        __builtin_amdgcn_s_setprio(0);
        // key mask: only the last tile can be partial (prefix mask)
        if (kt == nkt - 1) {
            #pragma unroll
            for (int f = 0; f < 4; ++f) {
                #pragma unroll
                for (int r = 0; r < 4; ++r) {
                    if (kmask[b_ * SS + kb + (f << 4) + (lg << 2) + r] == 0)
                        sf[f][r] = -1e30f;
                }
            }
        }
        // P = exp2(S) (no max subtraction: scores bounded, f32 has headroom)
        #pragma unroll
        for (int f = 0; f < 4; ++f)
            #pragma unroll
            for (int r = 0; r < 4; ++r)
                sf[f][r] = exp2_hw(sf[f][r]);

        // in-register P -> PV A-fragments (no LDS round-trip)
        uint32_t wv[4][2];
        #pragma unroll
        for (int f = 0; f < 4; ++f) {
            wv[f][0] = cvt_pk_bf16(sf[f][0], sf[f][1]);
            wv[f][1] = cvt_pk_bf16(sf[f][2], sf[f][3]);
        }
        bf16x8 pa[2];
        #pragma unroll
        for (int ks2 = 0; ks2 < 2; ++ks2) {
            uint32_t u0, u1, u2, u3;
            {
                uint32_t A = wv[2 * ks2][0], B = wv[2 * ks2 + 1][0];
                asm("v_permlane32_swap_b32 %0, %1" : "+v"(A), "+v"(B));
                asm("v_permlane16_swap_b32 %0, %1" : "+v"(A), "+v"(B));
                u0 = A; u2 = B;
            }
            {
                uint32_t A = wv[2 * ks2][1], B = wv[2 * ks2 + 1][1];
                asm("v_permlane32_swap_b32 %0, %1" : "+v"(A), "+v"(B));
                asm("v_permlane16_swap_b32 %0, %1" : "+v"(A), "+v"(B));
                u1 = A; u3 = B;
            }
            union { uint32_t q[4]; bf16x8 v; } cv;
            cv.q[0] = u0; cv.q[1] = u1; cv.q[2] = u2; cv.q[3] = u3;
            pa[ks2] = cv.v;
        }

        // O += P V ; l += P . ones   (A = pa[ks] in registers, B = V^T / ones)
        __builtin_amdgcn_s_setprio(1);
        #pragma unroll
        for (int ks = 0; ks < 2; ++ks) {
            lacc = __builtin_amdgcn_mfma_f32_16x16x32_bf16(pa[ks], vones, lacc, 0, 0, 0);
            #pragma unroll
            for (int nf = 0; nf < 4; ++nf) {
                const int vrow = (nf << 4) + lr;
                const int vcol = ((ks << 6) + (lg << 4)) ^ ((vrow & 7) << 4);
                bf16x8 vb = *(const bf16x8*)((const char*)Vs[cur] + vrow * 128 + vcol);
                o[nf] = __builtin_amdgcn_mfma_f32_16x16x32_bf16(pa[ks], vb, o[nf], 0, 0, 0);
            }
        }
        __builtin_amdgcn_s_setprio(0);

        // counted wait BEFORE barrier: tile kt+1 must be landed (all waves),
        // tile kt+2's 2 loads may stay in flight
        if (kt + 2 < nkt) { asm volatile("s_waitcnt vmcnt(2)" ::: "memory"); }
        else              { asm volatile("s_waitcnt vmcnt(0)" ::: "memory"); }
        __builtin_amdgcn_sched_barrier(0);
        __builtin_amdgcn_s_barrier();
        cur = nxt;
    }

    // normalize, apply query mask, store bf16 into X2 [b][s][h*64+d]
    #pragma unroll
    for (int r = 0; r < 4; ++r) {
        const int q = q0 + (w << 4) + (lg << 2) + r;
        float l = lacc[r];
        float inv = (l > 0.f) ? __builtin_amdgcn_rcpf(l) : 0.f;
        if (qmask[b_ * SS + q] == 0) inv = 0.f;
        #pragma unroll
        for (int nf = 0; nf < 4; ++nf)
            X2[((size_t)b_ * SS + q) * DD + (h << 6) + (nf << 4) + lr] = f2b_hw(o[nf][r] * inv);
    }
}

// ---------------- output projection GEMM + bias -> fp32 --------------------
// (Round-11 version, verbatim — XCD-swizzled 128^2, 3-buffer tail-vmcnt.)
__global__ __launch_bounds__(256, 2) void k_gemm_out(
    const u16* __restrict__ X2, const u16* __restrict__ Wot,
    const float* __restrict__ bo, float* __restrict__ out)
{
    __shared__ u16 As3[3][128 * 64];   // 48KB: A triple-buffer
    __shared__ u16 Bs3[3][128 * 64];   // 48KB: B triple-buffer
    const int flat = blockIdx.y * 8 + blockIdx.x;
    const int xcd = flat & 7, idx = flat >> 3;
    const int by = (xcd << 2) + (idx >> 3);     // [0,32)
    const int bx = idx & 7;                     // [0,8)
    const int m0 = by * 128, n0 = bx * 128;
    const int t = threadIdx.x;
    const int lane = t & 63, w = t >> 6;
    const int wm = (w >> 1) << 6, wn = (w & 1) << 6;
    const int lr = lane & 15, lg = lane >> 4;

    f32x4 acc[4][4] = {};

    // 8 loads/thread per stage (4 A + 4 B)
    auto stage = [&](int buf, int kt) {
        #pragma unroll
        for (int i = 0; i < 4; ++i) {
            int off = (t + (i << 8)) << 4;
            int row = off >> 7, colb = off & 127;
            int scol = colb ^ ((row & 7) << 4);
            gload_lds16(X2 + (size_t)(m0 + row) * DD + (kt << 6) + (scol >> 1), (char*)As3[buf] + off);
            gload_lds16(Wot + (size_t)(n0 + row) * DD + (kt << 6) + (scol >> 1), (char*)Bs3[buf] + off);
        }
    };

    // prologue: tiles 0,1; drain tile 0 (8 oldest), keep tile 1 in flight
    stage(0, 0); stage(1, 1);
    asm volatile("s_waitcnt vmcnt(8)" ::: "memory");
    __builtin_amdgcn_sched_barrier(0);
    __builtin_amdgcn_s_barrier();

    int cur = 0;
    #pragma unroll 1
    for (int kt = 0; kt < 16; ++kt) {
        const int nxt = (cur == 2) ? 0 : cur + 1;
        const int nx2 = (nxt == 2) ? 0 : nxt + 1;
        if (kt + 2 < 16) stage(nx2, kt + 2);   // buf of kt-1, WAR 1 barrier back

        __builtin_amdgcn_s_setprio(1);
        #pragma unroll
        for (int ks = 0; ks < 2; ++ks) {
            bf16x8 a[4], b[4];
            #pragma unroll
            for (int i = 0; i < 4; ++i) {
                const int row = wm + (i << 4) + lr;
                a[i] = *(const bf16x8*)((const char*)As3[cur] + row * 128 + (((ks << 6) + (lg << 4)) ^ ((row & 7) << 4)));
            }
            #pragma unroll
            for (int i = 0; i < 4; ++i) {
                const int row = wn + (i << 4) + lr;
                b[i] = *(const bf16x8*)((const char*)Bs3[cur] + row * 128 + (((ks << 6) + (lg << 4)) ^ ((row & 7) << 4)));
            }
            #pragma unroll
            for (int mi = 0; mi < 4; ++mi)
                #pragma unroll
                for (int ni = 0; ni < 4; ++ni)
                    acc[mi][ni] = __builtin_amdgcn_mfma_f32_16x16x32_bf16(a[mi], b[ni], acc[mi][ni], 0, 0, 0);
        }
        __builtin_amdgcn_s_setprio(0);

        // counted wait BEFORE barrier: tile kt+1 landed for all waves;
        // tile kt+2's 8 loads stay in flight across the barrier
        if (kt < 15) {
            if (kt + 2 < 16) { asm volatile("s_waitcnt vmcnt(8)" ::: "memory"); }
            else             { asm volatile("s_waitcnt vmcnt(0)" ::: "memory"); }
            __builtin_amdgcn_sched_barrier(0);
            __builtin_amdgcn_s_barrier();
        }
        cur = nxt;
    }

    #pragma unroll
    for (int mi = 0; mi < 4; ++mi) {
        #pragma unroll
        for (int ni = 0; ni < 4; ++ni) {
            const int n = n0 + wn + (ni << 4) + lr;
            const int mbase = m0 + wm + (mi << 4) + (lg << 2);
            const float bias = bo[n];
            #pragma unroll
            for (int r = 0; r < 4; ++r)
                out[(size_t)(mbase + r) * DD + n] = acc[mi][ni][r] + bias;
        }
    }
}

extern "C" void kernel_launch(void* const* d_in, const int* in_sizes, int n_in,
                              void* d_out, int out_size, void* d_ws, size_t ws_size,
                              hipStream_t stream) {
    const float* hs = (const float*)d_in[0];
    const float* Wq = (const float*)d_in[1];
    const float* bq = (const float*)d_in[2];
    const float* Wk = (const float*)d_in[3];
    const float* bk = (const float*)d_in[4];
    const float* Wv = (const float*)d_in[5];
    const float* bv = (const float*)d_in[6];
    const float* Wo = (const float*)d_in[7];
    const float* bo = (const float*)d_in[8];
    const int* qm = (const int*)d_in[9];
    const int* km = (const int*)d_in[10];
    float* out = (float*)d_out;

    char* ws = (char*)d_ws;
    const size_t MB = 1024 * 1024;
    u16* Xb  = (u16*)(ws + 0);        // [4096][1024]        8 MB
    u16* Wt3 = (u16*)(ws + 8 * MB);   // [3072][1024] q|k|v  6 MB
    u16* Wot = (u16*)(ws + 14 * MB);  // [1024][1024]        2 MB
    u16* Qb  = (u16*)(ws + 16 * MB);  // [B][H][S][HD]       8 MB
    u16* Kb  = (u16*)(ws + 24 * MB);  // [B][H][S][HD]       8 MB
    u16* Vt  = (u16*)(ws + 32 * MB);  // [B][H][HD][S]       8 MB
    u16* X2  = (u16*)(ws + 40 * MB);  // [4096][1024]        8 MB

    k_prep<<<dim3(32, 32, 5), dim3(32, 8), 0, stream>>>(hs, Xb, Wq, Wk, Wv, Wo, Wt3, Wot);
    k_gemm_qkv<<<dim3(16, 16), dim3(512), 0, stream>>>(Xb, Wt3, bq, bk, bv, Qb, Kb, Vt);
    k_attn<<<dim3(512), dim3(512), 0, stream>>>(Qb, Kb, Vt, qm, km, X2);
    k_gemm_out<<<dim3(8, 32), dim3(256), 0, stream>>>(X2, Wot, bo, out);
}